// Round 1
// baseline (15551.543 us; speedup 1.0000x reference)
//
#include <hip/hip_runtime.h>
#include <cstdint>
#include <cstddef>

typedef unsigned short u16;
typedef unsigned int u32;
typedef __bf16 bf16x8 __attribute__((ext_vector_type(8)));
typedef float f32x16 __attribute__((ext_vector_type(16)));

// ---------- small helpers ----------
static __device__ __forceinline__ u16 f2b(float f) {
  u32 x = __builtin_bit_cast(u32, f);
  return (u16)((x + 0x7FFFu + ((x >> 16) & 1u)) >> 16);  // RNE
}
static __device__ __forceinline__ float b2f(u16 u) {
  return __builtin_bit_cast(float, ((u32)u) << 16);
}
static __device__ __forceinline__ float blo(u32 w) {
  return __builtin_bit_cast(float, w << 16);
}
static __device__ __forceinline__ float bhi(u32 w) {
  return __builtin_bit_cast(float, w & 0xffff0000u);
}
static __device__ __forceinline__ void gl_lds16(const u16* g, u16* l) {
  __builtin_amdgcn_global_load_lds((const __attribute__((address_space(1))) u32*)g,
                                   (__attribute__((address_space(3))) u32*)l, 16, 0, 0);
}
static __device__ __forceinline__ f32x16 mfma16(bf16x8 a, bf16x8 b, f32x16 c) {
  return __builtin_amdgcn_mfma_f32_32x32x16_bf16(a, b, c, 0, 0, 0);
}
static __device__ __forceinline__ bf16x8 ldsfrag(const u16* p) {
  return *reinterpret_cast<const bf16x8*>(p);
}
static __device__ __forceinline__ f32x16 zero16() {
  f32x16 z;
#pragma unroll
  for (int i = 0; i < 16; ++i) z[i] = 0.0f;
  return z;
}
static __device__ __forceinline__ float sigm(float x) {
  return 1.0f / (1.0f + __expf(-x));
}
static __device__ __forceinline__ float tanh_fast(float x) {
  return 2.0f / (1.0f + __expf(-2.0f * x)) - 1.0f;
}

// ---------- weight packing ----------
// Blob layout (16B units): [kk][nb][nt(8)][ksub(2)][khalf(2)][jl(32)]
// unit holds W[nb*256 + nt*32 + jl][kk*32 + ksub*16 + khalf*8 + 0..7] (bf16)
__global__ void pack_tree(u16* __restrict__ dst, const float* __restrict__ src,
                          int NB, int K) {
  int u = blockIdx.x * 256 + threadIdx.x;
  int total = NB * 256 * (K / 8);
  if (u >= total) return;
  int u2 = u & 1023;
  int q = u >> 10;
  int nb = q % NB, kk = q / NB;
  int jl = u2 & 31;
  int khalf = (u2 >> 5) & 1;
  int ksub = (u2 >> 6) & 1;
  int nt = u2 >> 7;
  int row = nb * 256 + nt * 32 + jl;
  int kc = kk * 32 + ksub * 16 + khalf * 8;
  const float* s = src + (size_t)row * K + kc;
  u16 t[8];
#pragma unroll
  for (int e = 0; e < 8; ++e) t[e] = f2b(s[e]);
  u32 w0 = (u32)t[0] | ((u32)t[1] << 16);
  u32 w1 = (u32)t[2] | ((u32)t[3] << 16);
  u32 w2 = (u32)t[4] | ((u32)t[5] << 16);
  u32 w3 = (u32)t[6] | ((u32)t[7] << 16);
  uint4 v = make_uint4(w0, w1, w2, w3);
  *reinterpret_cast<uint4*>(dst + (size_t)u * 8) = v;
}

// GRU weight blob: [kk(34)][jb(16)][jg2(2)][s(3)][ksub(2)][khalf(2)][jl(32)] 16B units
// s=0:r s=1:z s=2:hn.  k<64 comes from W_ih (zeros for s=2), k>=64 from W_hh.
__global__ void pack_gru(u16* __restrict__ dst, const float* __restrict__ Wih,
                         const float* __restrict__ Whh) {
  int u = blockIdx.x * 256 + threadIdx.x;
  if (u >= 34 * 16 * 768) return;
  int u2 = u % 768;
  int t = u / 768;
  int jb = t & 15, kk = t >> 4;
  int jl = u2 & 31;
  int q = u2 >> 5;
  int khalf = q & 1; q >>= 1;
  int ksub = q & 1; q >>= 1;
  int s = q % 3, jg2 = q / 3;
  int j = jb * 64 + jg2 * 32 + jl;
  int k = kk * 32 + ksub * 16 + khalf * 8;
  u16 tm[8];
  if (k < 64) {
    if (s == 2) {
#pragma unroll
      for (int e = 0; e < 8; ++e) tm[e] = 0;
    } else {
      const float* p = Wih + (size_t)(s * 1024 + j) * 64 + k;
#pragma unroll
      for (int e = 0; e < 8; ++e) tm[e] = f2b(p[e]);
    }
  } else {
    const float* p = Whh + (size_t)(s * 1024 + j) * 1024 + (k - 64);
#pragma unroll
    for (int e = 0; e < 8; ++e) tm[e] = f2b(p[e]);
  }
  u32 w0 = (u32)tm[0] | ((u32)tm[1] << 16);
  u32 w1 = (u32)tm[2] | ((u32)tm[3] << 16);
  u32 w2 = (u32)tm[4] | ((u32)tm[5] << 16);
  u32 w3 = (u32)tm[6] | ((u32)tm[7] << 16);
  *reinterpret_cast<uint4*>(dst + (size_t)u * 8) = make_uint4(w0, w1, w2, w3);
}

__global__ void pack_bias(float* br, float* bz, float* bhn, float* bt3, float* bt4,
                          const float* b_ih, const float* b_hh,
                          const float* b3a, const float* b3l,
                          const float* b2ra, const float* b2la,
                          const float* b2rl, const float* b2ll) {
  int i = blockIdx.x * 256 + threadIdx.x;
  if (i >= 1024) return;
  br[i] = b_ih[i] + b_hh[i];
  bz[i] = b_ih[1024 + i] + b_hh[1024 + i];
  bhn[i] = b_hh[2048 + i];
  bt3[i] = (i < 512) ? b3a[i] : b3l[i - 512];
  int sg = i >> 8, sc = i & 255;
  const float* b2 = (sg == 0) ? b2ra : (sg == 1) ? b2la : (sg == 2) ? b2rl : b2ll;
  bt4[i] = b2[sc];
}

__global__ void init_h(float* __restrict__ hf, u16* __restrict__ hb,
                       const float* __restrict__ h0) {
  size_t i = (size_t)blockIdx.x * 256 + threadIdx.x;
  float v = h0[i];
  hf[i] = v;
  hb[i] = f2b(v);
}

__global__ void init_x(float* __restrict__ xf, u16* __restrict__ xb,
                       const float* __restrict__ gt) {
  int i = blockIdx.x * 256 + threadIdx.x;  // 4096*64
  int b = i >> 6, c = i & 63;
  float v = gt[(size_t)b * 128 * 64 + c];  // gt[:,0,:]
  xf[i] = v;
  xb[i] = f2b(v);
}

// ---------- generic segment GEMM: out[m, colBase+n] = act[m, actOff+k] @ W^T + bias ----------
// block tile 64(M) x 256(N), 4 waves, wave tile 64x64 (2 m-tiles x 2 n-tiles of 32x32).
// out is bf16, row stride 1024. bias indexed by global out column.
__global__ __launch_bounds__(256, 2) void tree_gemm(
    const u16* __restrict__ act, int actLD, int actSegStride,
    const u16* __restrict__ wblob, int nbPerSeg, int KS,
    const float* __restrict__ bias, u16* __restrict__ outp, int NperSeg) {
  __shared__ __align__(16) u16 lds[2][10240];  // per buf: A=2048 u16 (4KB), B=8192 u16 (16KB)
  const int tid = threadIdx.x;
  const int lane = tid & 63, wave = tid >> 6;
  const int mBase = blockIdx.x * 64;
  const int seg = blockIdx.y / nbPerSeg, nb = blockIdx.y % nbPerSeg;
  const int actOff = seg * actSegStride;
  const u16* wseg = wblob + (size_t)seg * KS * nbPerSeg * 8192;
  const int outColBase = seg * NperSeg + nb * 256;

  f32x16 acc00 = zero16(), acc01 = zero16(), acc10 = zero16(), acc11 = zero16();

  auto stage = [&](int kk, int buf) {
    const u16* wsl = wseg + ((size_t)kk * nbPerSeg + nb) * 8192;
#pragma unroll
    for (int i = 0; i < 5; ++i) {
      int is = wave + 4 * i;
      if (is < 4) {
        int mt = is >> 1, ks = is & 1;
        int row = mBase + mt * 32 + (lane & 31);
        int kc = kk * 32 + ks * 16 + (lane >> 5) * 8;
        gl_lds16(act + (size_t)row * actLD + actOff + kc, &lds[buf][is * 512]);
      } else {
        int b = is - 4;
        gl_lds16(wsl + (size_t)(b * 64 + lane) * 8, &lds[buf][2048 + b * 512]);
      }
    }
  };

  auto compute = [&](int buf) {
    const u16* L = lds[buf];
#pragma unroll
    for (int ks = 0; ks < 2; ++ks) {
      bf16x8 a0 = ldsfrag(L + (0 * 2 + ks) * 512 + lane * 8);
      bf16x8 a1 = ldsfrag(L + (1 * 2 + ks) * 512 + lane * 8);
      bf16x8 b0 = ldsfrag(L + 2048 + ((wave * 2 + 0) * 2 + ks) * 512 + lane * 8);
      bf16x8 b1 = ldsfrag(L + 2048 + ((wave * 2 + 1) * 2 + ks) * 512 + lane * 8);
      acc00 = mfma16(a0, b0, acc00);
      acc01 = mfma16(a0, b1, acc01);
      acc10 = mfma16(a1, b0, acc10);
      acc11 = mfma16(a1, b1, acc11);
    }
  };

  stage(0, 0);
  for (int kk = 0; kk < KS; ++kk) {
    __syncthreads();
    if (kk + 1 < KS) stage(kk + 1, (kk + 1) & 1);
    compute(kk & 1);
  }

  // epilogue: C/D layout col=lane&31, row=(r&3)+8*(r>>2)+4*(lane>>5)
  const int colW = outColBase + wave * 64;
#pragma unroll
  for (int mt = 0; mt < 2; ++mt) {
    int rb = mBase + mt * 32 + 4 * (lane >> 5);
#pragma unroll
    for (int ntl = 0; ntl < 2; ++ntl) {
      f32x16 c = (mt == 0) ? (ntl == 0 ? acc00 : acc01) : (ntl == 0 ? acc10 : acc11);
      int col = colW + ntl * 32 + (lane & 31);
      float bv = bias[col];
#pragma unroll
      for (int r = 0; r < 16; ++r) {
        int row = rb + (r & 3) + 8 * (r >> 2);
        outp[(size_t)row * 1024 + col] = f2b(c[r] + bv);
      }
    }
  }
}

// ---------- fused GRU gates GEMM + gate math ----------
// block tile 128(M) x 64(j) [j covers 3 gate sets r/z/hn], 4 waves (2m x 2jg),
// wave tile 64 rows x 32 j x 3 sets. K = 1088 ([x(64) | h(1024)]), KS=34.
__global__ __launch_bounds__(256, 2) void gru_gemm(
    const u16* __restrict__ xb, const u16* __restrict__ hbIn,
    float* __restrict__ hf, const u16* __restrict__ ip,
    const u16* __restrict__ wgru,
    const float* __restrict__ br, const float* __restrict__ bz,
    const float* __restrict__ bhn, u16* __restrict__ hbOut) {
  __shared__ __align__(16) u16 lds[2][10240];  // A=4096 u16 (8KB), B=6144 u16 (12KB)
  const int tid = threadIdx.x;
  const int lane = tid & 63, wave = tid >> 6;
  const int wm = wave >> 1, wjg = wave & 1;
  const int mBase = blockIdx.x * 128;
  const int jb = blockIdx.y;

  f32x16 aR0 = zero16(), aZ0 = zero16(), aN0 = zero16();
  f32x16 aR1 = zero16(), aZ1 = zero16(), aN1 = zero16();

  auto stage = [&](int kk, int buf) {
#pragma unroll
    for (int i = 0; i < 5; ++i) {
      int is = wave + 4 * i;
      if (is < 8) {
        int mt = is >> 1, ks = is & 1;
        int row = mBase + mt * 32 + (lane & 31);
        const u16* g;
        if (kk < 2)
          g = xb + (size_t)row * 64 + kk * 32 + ks * 16 + (lane >> 5) * 8;
        else
          g = hbIn + (size_t)row * 1024 + (kk - 2) * 32 + ks * 16 + (lane >> 5) * 8;
        gl_lds16(g, &lds[buf][is * 512]);
      } else {
        int b = is - 8;
        const u16* g = wgru + ((size_t)(kk * 16 + jb) * 768 + b * 64 + lane) * 8;
        gl_lds16(g, &lds[buf][4096 + b * 512]);
      }
    }
  };

  auto compute = [&](int buf) {
    const u16* L = lds[buf];
#pragma unroll
    for (int ks = 0; ks < 2; ++ks) {
      bf16x8 a0 = ldsfrag(L + ((wm * 2 + 0) * 2 + ks) * 512 + lane * 8);
      bf16x8 a1 = ldsfrag(L + ((wm * 2 + 1) * 2 + ks) * 512 + lane * 8);
      const u16* Bp = L + 4096;
      bf16x8 bR = ldsfrag(Bp + ((wjg * 3 + 0) * 2 + ks) * 512 + lane * 8);
      bf16x8 bZ = ldsfrag(Bp + ((wjg * 3 + 1) * 2 + ks) * 512 + lane * 8);
      bf16x8 bN = ldsfrag(Bp + ((wjg * 3 + 2) * 2 + ks) * 512 + lane * 8);
      aR0 = mfma16(a0, bR, aR0);
      aZ0 = mfma16(a0, bZ, aZ0);
      aN0 = mfma16(a0, bN, aN0);
      aR1 = mfma16(a1, bR, aR1);
      aZ1 = mfma16(a1, bZ, aZ1);
      aN1 = mfma16(a1, bN, aN1);
    }
  };

  stage(0, 0);
  for (int kk = 0; kk < 34; ++kk) {
    __syncthreads();
    if (kk + 1 < 34) stage(kk + 1, (kk + 1) & 1);
    compute(kk & 1);
  }

  const int j = jb * 64 + wjg * 32 + (lane & 31);
  const float brv = br[j], bzv = bz[j], bhv = bhn[j];
#pragma unroll
  for (int mt = 0; mt < 2; ++mt) {
    f32x16 cr = mt ? aR1 : aR0;
    f32x16 cz = mt ? aZ1 : aZ0;
    f32x16 cn = mt ? aN1 : aN0;
    int rb = mBase + wm * 64 + mt * 32 + 4 * (lane >> 5);
#pragma unroll
    for (int r = 0; r < 16; ++r) {
      int row = rb + (r & 3) + 8 * (r >> 2);
      size_t idx = (size_t)row * 1024 + j;
      float rv = sigm(cr[r] + brv);
      float zv = sigm(cz[r] + bzv);
      float hnv = cn[r] + bhv;
      float inv = b2f(ip[idx]);  // x@W_ih_n + b_ih_n (precomputed)
      float nv = tanh_fast(inv + rv * hnv);
      float ho = hf[idx];
      float hv = (1.0f - zv) * nv + zv * ho;
      hf[idx] = hv;
      hbOut[idx] = f2b(hv);
    }
  }
}

// ---------- level-1 limb layer + torso average + residual + output ----------
// 4 rows per block, thread (row, c). lvl1 input: [4096][1024] bf16.
__global__ __launch_bounds__(256, 2) void k5_kernel(
    const u16* __restrict__ lvl1, float* __restrict__ xf, u16* __restrict__ xb,
    float* __restrict__ outp, int t,
    const float* __restrict__ w_t, const float* __restrict__ w_la,
    const float* __restrict__ w_ra, const float* __restrict__ w_ll,
    const float* __restrict__ w_rl,
    const float* __restrict__ b_t, const float* __restrict__ b_la,
    const float* __restrict__ b_ra, const float* __restrict__ b_ll,
    const float* __restrict__ b_rl) {
  __shared__ __align__(16) u16 wlds[64 * 128];  // torso16, larm9, rarm9, lleg15, rleg15
  __shared__ __align__(16) u16 alds[4 * 1024];
  const int tid = threadIdx.x;
  for (int i = tid; i < 8192; i += 256) {
    int rw = i >> 7, k = i & 127;
    float v;
    if (rw < 16) v = w_t[rw * 128 + k];
    else if (rw < 25) v = w_la[(rw - 16) * 128 + k];
    else if (rw < 34) v = w_ra[(rw - 25) * 128 + k];
    else if (rw < 49) v = w_ll[(rw - 34) * 128 + k];
    else v = w_rl[(rw - 49) * 128 + k];
    wlds[i] = f2b(v);
  }
  const u16* ab = lvl1 + (size_t)blockIdx.x * 4 * 1024;
  for (int i = tid; i < 512; i += 256)
    *reinterpret_cast<uint4*>(alds + i * 8) =
        *reinterpret_cast<const uint4*>(ab + i * 8);
  __syncthreads();

  int rloc = tid >> 6, c = tid & 63;
  int grow = blockIdx.x * 4 + rloc;
  int wrow, abase = 0, nseg = 1;
  float bv, scale = 1.0f;
  if (c < 13)      { wrow = c;            nseg = 4; scale = 0.25f; bv = b_t[c]; }
  else if (c < 22) { wrow = 16 + (c - 13); abase = 256; bv = b_la[c - 13]; }
  else if (c < 31) { wrow = 25 + (c - 22); abase = 0;   bv = b_ra[c - 22]; }
  else if (c < 46) { wrow = 34 + (c - 31); abase = 768; bv = b_ll[c - 31]; }
  else if (c < 61) { wrow = 49 + (c - 46); abase = 512; bv = b_rl[c - 46]; }
  else             { wrow = 13 + (c - 61); nseg = 4; scale = 0.25f; bv = b_t[13 + (c - 61)]; }

  float acc = 0.0f;
  for (int s = 0; s < nseg; ++s) {
    int base = (nseg == 4) ? (128 + s * 256) : abase;
#pragma unroll
    for (int k8 = 0; k8 < 16; ++k8) {
      uint4 av = *reinterpret_cast<const uint4*>(alds + rloc * 1024 + base + k8 * 8);
      uint4 wv = *reinterpret_cast<const uint4*>(wlds + wrow * 128 + k8 * 8);
      acc += blo(av.x) * blo(wv.x) + bhi(av.x) * bhi(wv.x);
      acc += blo(av.y) * blo(wv.y) + bhi(av.y) * bhi(wv.y);
      acc += blo(av.z) * blo(wv.z) + bhi(av.z) * bhi(wv.z);
      acc += blo(av.w) * blo(wv.w) + bhi(av.w) * bhi(wv.w);
    }
  }
  size_t xi = (size_t)grow * 64 + c;
  float v = acc * scale + bv + xf[xi];
  outp[((size_t)grow * 128 + t) * 64 + c] = v;
  xf[xi] = v;
  xb[xi] = f2b(v);
}

// ---------- host ----------
extern "C" void kernel_launch(void* const* d_in, const int* in_sizes, int n_in,
                              void* d_out, int out_size, void* d_ws, size_t ws_size,
                              hipStream_t stream) {
  const float* h0   = (const float*)d_in[0];
  const float* gt   = (const float*)d_in[1];
  const float* Wih  = (const float*)d_in[2];
  const float* Whh  = (const float*)d_in[3];
  const float* bih  = (const float*)d_in[4];
  const float* bhh  = (const float*)d_in[5];
  const float* w4   = (const float*)d_in[6];
  const float* b4   = (const float*)d_in[7];
  const float* w3a  = (const float*)d_in[8];
  const float* b3a  = (const float*)d_in[9];
  const float* w3l  = (const float*)d_in[10];
  const float* b3l  = (const float*)d_in[11];
  const float* w2ra = (const float*)d_in[12];
  const float* b2ra = (const float*)d_in[13];
  const float* w2la = (const float*)d_in[14];
  const float* b2la = (const float*)d_in[15];
  const float* w2rl = (const float*)d_in[16];
  const float* b2rl = (const float*)d_in[17];
  const float* w2ll = (const float*)d_in[18];
  const float* b2ll = (const float*)d_in[19];
  const float* w1ra = (const float*)d_in[20];
  const float* b1ra = (const float*)d_in[21];
  const float* w1la = (const float*)d_in[22];
  const float* b1la = (const float*)d_in[23];
  const float* w1rl = (const float*)d_in[24];
  const float* b1rl = (const float*)d_in[25];
  const float* w1ll = (const float*)d_in[26];
  const float* b1ll = (const float*)d_in[27];
  const float* w1t  = (const float*)d_in[28];
  const float* b1t  = (const float*)d_in[29];
  float* out = (float*)d_out;

  char* ws = (char*)d_ws;
  size_t off = 0;
  auto alloc = [&](size_t b) {
    off = (off + 255) & ~(size_t)255;
    char* p = ws + off;
    off += b;
    return p;
  };

  float* hf  = (float*)alloc(4096UL * 1024 * 4);
  u16* hb0 = (u16*)alloc(4096UL * 1024 * 2);
  u16* hb1 = (u16*)alloc(4096UL * 1024 * 2);
  float* xf = (float*)alloc(4096UL * 64 * 4);
  u16* xb  = (u16*)alloc(4096UL * 64 * 2);
  u16* ip  = (u16*)alloc(4096UL * 1024 * 2);
  u16* t0  = (u16*)alloc(4096UL * 1024 * 2);
  u16* t1  = (u16*)alloc(4096UL * 1024 * 2);
  u16* wgru = (u16*)alloc(34UL * 16 * 768 * 16);
  u16* wb0  = (u16*)alloc(2UL * 4 * 8192 * 2);
  u16* wb4  = (u16*)alloc(32UL * 4 * 8192 * 2);
  u16* wb3  = (u16*)alloc(2UL * 16 * 2 * 8192 * 2);
  u16* wb2  = (u16*)alloc(4UL * 8 * 1 * 8192 * 2);
  float* brp  = (float*)alloc(1024 * 4);
  float* bzp  = (float*)alloc(1024 * 4);
  float* bhnp = (float*)alloc(1024 * 4);
  float* bt3p = (float*)alloc(1024 * 4);
  float* bt4p = (float*)alloc(1024 * 4);
  (void)ws_size; (void)in_sizes; (void)n_in; (void)out_size;

  // ----- once-per-call prep (deterministic, graph-capturable) -----
  pack_gru<<<dim3((34 * 16 * 768) / 256), 256, 0, stream>>>(wgru, Wih, Whh);
  pack_tree<<<dim3(32), 256, 0, stream>>>(wb0, Wih + 2048 * 64, 4, 64);
  pack_tree<<<dim3(512), 256, 0, stream>>>(wb4, w4, 4, 1024);
  pack_tree<<<dim3(128), 256, 0, stream>>>(wb3, w3a, 2, 512);
  pack_tree<<<dim3(128), 256, 0, stream>>>(wb3 + 262144, w3l, 2, 512);
  pack_tree<<<dim3(32), 256, 0, stream>>>(wb2 + 0 * 65536, w2ra, 1, 256);
  pack_tree<<<dim3(32), 256, 0, stream>>>(wb2 + 1 * 65536, w2la, 1, 256);
  pack_tree<<<dim3(32), 256, 0, stream>>>(wb2 + 2 * 65536, w2rl, 1, 256);
  pack_tree<<<dim3(32), 256, 0, stream>>>(wb2 + 3 * 65536, w2ll, 1, 256);
  pack_bias<<<dim3(4), 256, 0, stream>>>(brp, bzp, bhnp, bt3p, bt4p, bih, bhh,
                                         b3a, b3l, b2ra, b2la, b2rl, b2ll);
  init_h<<<dim3(16384), 256, 0, stream>>>(hf, hb0, h0);
  init_x<<<dim3(1024), 256, 0, stream>>>(xf, xb, gt);

  // ----- 128 sequential steps -----
  for (int t = 0; t < 128; ++t) {
    u16* hcur = (t & 1) ? hb1 : hb0;
    u16* hnext = (t & 1) ? hb0 : hb1;
    // K0: in_pre = x @ W_ih_n^T + b_ih_n
    tree_gemm<<<dim3(64, 4), 256, 0, stream>>>(xb, 64, 0, wb0, 4, 2,
                                               bih + 2048, ip, 1024);
    // K1: fused GRU gates + update
    gru_gemm<<<dim3(32, 16), 256, 0, stream>>>(xb, hcur, hf, ip, wgru,
                                               brp, bzp, bhnp, hnext);
    // K2: fb = h @ w4^T + b4
    tree_gemm<<<dim3(64, 4), 256, 0, stream>>>(hnext, 1024, 0, wb4, 4, 32,
                                               b4, t0, 1024);
    // K3: ub|lb = fb halves @ w3_{arm,leg}^T
    tree_gemm<<<dim3(64, 4), 256, 0, stream>>>(t0, 1024, 512, wb3, 2, 16,
                                               bt3p, t1, 512);
    // K4: level-2 (4 segments of 256)
    tree_gemm<<<dim3(64, 4), 256, 0, stream>>>(t1, 1024, 256, wb2, 1, 8,
                                               bt4p, t0, 256);
    // K5: limb layer + torso avg + residual + output write
    k5_kernel<<<dim3(1024), 256, 0, stream>>>(t0, xf, xb, out, t,
                                              w1t, w1la, w1ra, w1ll, w1rl,
                                              b1t, b1la, b1ra, b1ll, b1rl);
  }
}